// Round 1
// baseline (224.280 us; speedup 1.0000x reference)
//
#include <hip/hip_runtime.h>
#include <stdint.h>

// ---------------- workspace layout (uint32 words) ----------------
#define HIST_SIZE   4096        // top-12-bit histogram
#define WS_HIST     0
#define WS_CAND_CNT 4096
#define WS_BIN      4097
#define WS_KINBIN   4098
#define WS_MEDIAN   4099

// monotonic key: orders float bit patterns ascending
__device__ __forceinline__ unsigned f2key(float f) {
    unsigned u = __float_as_uint(f);
    return (u & 0x80000000u) ? ~u : (u | 0x80000000u);
}

// ---------------- pass 1: histogram of top 12 bits ----------------
__global__ __launch_bounds__(256) void k_hist(const float* __restrict__ x,
                                              unsigned* __restrict__ ws, int n4) {
    __shared__ unsigned lh[HIST_SIZE];
    for (int i = threadIdx.x; i < HIST_SIZE; i += 256) lh[i] = 0u;
    __syncthreads();
    const float4* x4 = (const float4*)x;
    int stride = gridDim.x * blockDim.x;
    for (int i = blockIdx.x * blockDim.x + threadIdx.x; i < n4; i += stride) {
        float4 v = x4[i];
        atomicAdd(&lh[f2key(v.x) >> 20], 1u);
        atomicAdd(&lh[f2key(v.y) >> 20], 1u);
        atomicAdd(&lh[f2key(v.z) >> 20], 1u);
        atomicAdd(&lh[f2key(v.w) >> 20], 1u);
    }
    __syncthreads();
    for (int i = threadIdx.x; i < HIST_SIZE; i += 256) {
        unsigned c = lh[i];
        if (c) atomicAdd(&ws[WS_HIST + i], c);
    }
}

// ---------------- find bin containing rank k ----------------
__global__ __launch_bounds__(256) void k_scan(unsigned* __restrict__ ws, unsigned k) {
    __shared__ unsigned partial[256];
    __shared__ unsigned base[256];
    int t = threadIdx.x;
    unsigned local[16];
    unsigned s = 0;
    #pragma unroll
    for (int j = 0; j < 16; ++j) { local[j] = ws[WS_HIST + t * 16 + j]; s += local[j]; }
    partial[t] = s;
    __syncthreads();
    if (t == 0) {
        unsigned run = 0;
        for (int i = 0; i < 256; ++i) { base[i] = run; run += partial[i]; }
    }
    __syncthreads();
    unsigned b = base[t];
    #pragma unroll
    for (int j = 0; j < 16; ++j) {
        unsigned nb = b + local[j];
        if (b <= k && k < nb) {
            ws[WS_BIN] = (unsigned)(t * 16 + j);
            ws[WS_KINBIN] = k - b;
        }
        b = nb;
    }
}

// ---------------- pass 2: collect candidates in selected bin ----------------
__global__ __launch_bounds__(256) void k_collect(const float* __restrict__ x,
                                                 unsigned* __restrict__ ws,
                                                 unsigned* __restrict__ cand, int n4) {
    unsigned B = ws[WS_BIN];
    const float4* x4 = (const float4*)x;
    int stride = gridDim.x * blockDim.x;
    for (int i = blockIdx.x * blockDim.x + threadIdx.x; i < n4; i += stride) {
        float4 v = x4[i];
        unsigned k0 = f2key(v.x), k1 = f2key(v.y), k2 = f2key(v.z), k3 = f2key(v.w);
        if ((k0 >> 20) == B) cand[atomicAdd(&ws[WS_CAND_CNT], 1u)] = k0;
        if ((k1 >> 20) == B) cand[atomicAdd(&ws[WS_CAND_CNT], 1u)] = k1;
        if ((k2 >> 20) == B) cand[atomicAdd(&ws[WS_CAND_CNT], 1u)] = k2;
        if ((k3 >> 20) == B) cand[atomicAdd(&ws[WS_CAND_CNT], 1u)] = k3;
    }
}

// ---------------- select low 20 bits (single block) ----------------
__global__ __launch_bounds__(256) void k_select(unsigned* __restrict__ ws,
                                                const unsigned* __restrict__ cand) {
    __shared__ unsigned h[1024];
    __shared__ unsigned sel1_s, k2_s;
    unsigned count = ws[WS_CAND_CNT];
    unsigned k = ws[WS_KINBIN];
    int t = threadIdx.x;
    // pass 1: bits [19:10]
    for (int i = t; i < 1024; i += 256) h[i] = 0u;
    __syncthreads();
    for (unsigned i = t; i < count; i += 256) atomicAdd(&h[(cand[i] >> 10) & 1023u], 1u);
    __syncthreads();
    if (t == 0) {
        unsigned run = 0;
        for (int i = 0; i < 1024; ++i) {
            unsigned nb = run + h[i];
            if (run <= k && k < nb) { sel1_s = (unsigned)i; k2_s = k - run; }
            run = nb;
        }
    }
    __syncthreads();
    unsigned sel1 = sel1_s, k2 = k2_s;
    // pass 2: bits [9:0]
    for (int i = t; i < 1024; i += 256) h[i] = 0u;
    __syncthreads();
    for (unsigned i = t; i < count; i += 256) {
        unsigned c = cand[i];
        if (((c >> 10) & 1023u) == sel1) atomicAdd(&h[c & 1023u], 1u);
    }
    __syncthreads();
    if (t == 0) {
        unsigned run = 0, sel2 = 0;
        for (int i = 0; i < 1024; ++i) {
            unsigned nb = run + h[i];
            if (run <= k2 && k2 < nb) sel2 = (unsigned)i;
            run = nb;
        }
        unsigned key = (ws[WS_BIN] << 20) | (sel1 << 10) | sel2;
        unsigned u = (key & 0x80000000u) ? (key & 0x7fffffffu) : ~key;
        ws[WS_MEDIAN] = u;
    }
}

// ---------------- fused threshold + 7x7 maxpool + mask ----------------
#define TX 128
#define TY 32
#define HX 134          // TX + 6
#define HXP 136         // padded stride
#define HY 38           // TY + 6
#define IMG_W 1024
#define IMG_H 1024

__global__ __launch_bounds__(256) void k_pool(const float* __restrict__ x,
                                              float* __restrict__ out,
                                              const unsigned* __restrict__ ws) {
    __shared__ float xt[HY][HXP];
    __shared__ float rm[HY][TX];
    float med = __uint_as_float(ws[WS_MEDIAN]);
    int c0 = blockIdx.x * TX;
    int r0 = blockIdx.y * TY;
    const float* img = x + (size_t)blockIdx.z * (IMG_W * IMG_H);
    float* outp = out + (size_t)blockIdx.z * (IMG_W * IMG_H);

    int rbase = threadIdx.x / 128;   // 0 or 1
    int c = threadIdx.x % 128;

    // load tile + halo, thresholded; out-of-image = -inf
    for (int rr = rbase; rr < HY; rr += 2) {
        int gr = r0 + rr - 3;
        {
            int gc = c0 + c - 3;
            float v = -INFINITY;
            if ((unsigned)gr < (unsigned)IMG_H && (unsigned)gc < (unsigned)IMG_W) {
                float f = img[gr * IMG_W + gc];
                v = (f > med) ? f : 0.0f;
            }
            xt[rr][c] = v;
        }
        if (c < 6) {
            int gc = c0 + c + 128 - 3;
            float v = -INFINITY;
            if ((unsigned)gr < (unsigned)IMG_H && (unsigned)gc < (unsigned)IMG_W) {
                float f = img[gr * IMG_W + gc];
                v = (f > med) ? f : 0.0f;
            }
            xt[rr][c + 128] = v;
        }
    }
    __syncthreads();

    // horizontal 7-max
    for (int rr = rbase; rr < HY; rr += 2) {
        float m = xt[rr][c];
        #pragma unroll
        for (int j = 1; j < 7; ++j) m = fmaxf(m, xt[rr][c + j]);
        rm[rr][c] = m;
    }
    __syncthreads();

    // vertical 7-max + mask + write
    for (int rr = rbase; rr < TY; rr += 2) {
        float y = rm[rr][c];
        #pragma unroll
        for (int j = 1; j < 7; ++j) y = fmaxf(y, rm[rr + j][c]);
        float v = xt[rr + 3][c + 3];
        outp[(r0 + rr) * IMG_W + (c0 + c)] = (v == y) ? v : 0.0f;
    }
}

extern "C" void kernel_launch(void* const* d_in, const int* in_sizes, int n_in,
                              void* d_out, int out_size, void* d_ws, size_t ws_size,
                              hipStream_t stream) {
    const float* x = (const float*)d_in[0];
    float* out = (float*)d_out;
    unsigned* ws = (unsigned*)d_ws;
    unsigned* cand = (unsigned*)d_out;   // scratch; fully overwritten by k_pool

    int n = in_sizes[0];                  // 16,777,216
    int n4 = n / 4;
    unsigned k = (unsigned)((n - 1) / 2); // lower median rank

    // zero hist + candidate counter
    hipMemsetAsync(d_ws, 0, (WS_CAND_CNT + 1) * sizeof(unsigned), stream);

    dim3 blk(256);
    k_hist<<<dim3(2048), blk, 0, stream>>>(x, ws, n4);
    k_scan<<<dim3(1), blk, 0, stream>>>(ws, k);
    k_collect<<<dim3(2048), blk, 0, stream>>>(x, ws, cand, n4);
    k_select<<<dim3(1), blk, 0, stream>>>(ws, cand);

    dim3 pgrid(IMG_W / TX, IMG_H / TY, 16);
    k_pool<<<pgrid, blk, 0, stream>>>(x, out, ws);
}

// Round 2
// 138.847 us; speedup vs baseline: 1.6153x; 1.6153x over previous
//
#include <hip/hip_runtime.h>
#include <stdint.h>

// ---------------- workspace layout (uint32 words) ----------------
#define HIST_SIZE   4096        // top-12-bit histogram
#define WS_HIST     0
#define WS_CAND_CNT 4096
#define WS_BIN      4097
#define WS_KINBIN   4098
#define WS_MEDIAN   4099

// monotonic key: orders float bit patterns ascending
__device__ __forceinline__ unsigned f2key(float f) {
    unsigned u = __float_as_uint(f);
    return (u & 0x80000000u) ? ~u : (u | 0x80000000u);
}

// 256-thread exclusive prefix sum (Hillis-Steele in LDS). tmp is 256 words.
__device__ __forceinline__ unsigned block_excl_scan(unsigned s, unsigned* tmp) {
    int t = threadIdx.x;
    tmp[t] = s;
    __syncthreads();
    unsigned acc = s;
    #pragma unroll
    for (int off = 1; off < 256; off <<= 1) {
        unsigned v = (t >= off) ? tmp[t - off] : 0u;
        __syncthreads();
        acc += v;
        tmp[t] = acc;
        __syncthreads();
    }
    return acc - s;   // exclusive prefix
}

// ---------------- pass 1: histogram of top 12 bits ----------------
__global__ __launch_bounds__(256) void k_hist(const float* __restrict__ x,
                                              unsigned* __restrict__ ws, int n4) {
    __shared__ unsigned lh[HIST_SIZE];
    for (int i = threadIdx.x; i < HIST_SIZE; i += 256) lh[i] = 0u;
    __syncthreads();
    const float4* x4 = (const float4*)x;
    int stride = gridDim.x * blockDim.x;
    for (int i = blockIdx.x * blockDim.x + threadIdx.x; i < n4; i += stride) {
        float4 v = x4[i];
        atomicAdd(&lh[f2key(v.x) >> 20], 1u);
        atomicAdd(&lh[f2key(v.y) >> 20], 1u);
        atomicAdd(&lh[f2key(v.z) >> 20], 1u);
        atomicAdd(&lh[f2key(v.w) >> 20], 1u);
    }
    __syncthreads();
    for (int i = threadIdx.x; i < HIST_SIZE; i += 256) {
        unsigned c = lh[i];
        if (c) atomicAdd(&ws[WS_HIST + i], c);
    }
}

// ---------------- find bin containing rank k (parallel scan) ----------------
__global__ __launch_bounds__(256) void k_scan(unsigned* __restrict__ ws, unsigned k) {
    __shared__ unsigned tmp[256];
    int t = threadIdx.x;
    unsigned local[16];
    unsigned s = 0;
    #pragma unroll
    for (int j = 0; j < 16; ++j) { local[j] = ws[WS_HIST + t * 16 + j]; s += local[j]; }
    unsigned b = block_excl_scan(s, tmp);
    #pragma unroll
    for (int j = 0; j < 16; ++j) {
        unsigned nb = b + local[j];
        if (b <= k && k < nb) {
            ws[WS_BIN] = (unsigned)(t * 16 + j);
            ws[WS_KINBIN] = k - b;
        }
        b = nb;
    }
}

// ---------------- pass 2: collect candidates in selected bin ----------------
__global__ __launch_bounds__(256) void k_collect(const float* __restrict__ x,
                                                 unsigned* __restrict__ ws,
                                                 unsigned* __restrict__ cand, int n4) {
    unsigned B = ws[WS_BIN];
    const float4* x4 = (const float4*)x;
    int stride = gridDim.x * blockDim.x;
    for (int i = blockIdx.x * blockDim.x + threadIdx.x; i < n4; i += stride) {
        float4 v = x4[i];
        unsigned k0 = f2key(v.x), k1 = f2key(v.y), k2 = f2key(v.z), k3 = f2key(v.w);
        if ((k0 >> 20) == B) cand[atomicAdd(&ws[WS_CAND_CNT], 1u)] = k0;
        if ((k1 >> 20) == B) cand[atomicAdd(&ws[WS_CAND_CNT], 1u)] = k1;
        if ((k2 >> 20) == B) cand[atomicAdd(&ws[WS_CAND_CNT], 1u)] = k2;
        if ((k3 >> 20) == B) cand[atomicAdd(&ws[WS_CAND_CNT], 1u)] = k3;
    }
}

// ---------------- select low 20 bits (single block, parallel scans) ----------------
__global__ __launch_bounds__(256) void k_select(unsigned* __restrict__ ws,
                                                const unsigned* __restrict__ cand) {
    __shared__ unsigned h[1024];
    __shared__ unsigned tmp[256];
    __shared__ unsigned sel1_s, k2_s, sel2_s;
    unsigned count = ws[WS_CAND_CNT];
    unsigned k = ws[WS_KINBIN];
    int t = threadIdx.x;

    // pass 1: bits [19:10]
    for (int i = t; i < 1024; i += 256) h[i] = 0u;
    __syncthreads();
    for (unsigned i = t; i < count; i += 256) atomicAdd(&h[(cand[i] >> 10) & 1023u], 1u);
    __syncthreads();
    {
        unsigned l0 = h[t * 4], l1 = h[t * 4 + 1], l2 = h[t * 4 + 2], l3 = h[t * 4 + 3];
        unsigned s = l0 + l1 + l2 + l3;
        unsigned b = block_excl_scan(s, tmp);
        unsigned nb;
        nb = b + l0; if (b <= k && k < nb) { sel1_s = t * 4 + 0; k2_s = k - b; } b = nb;
        nb = b + l1; if (b <= k && k < nb) { sel1_s = t * 4 + 1; k2_s = k - b; } b = nb;
        nb = b + l2; if (b <= k && k < nb) { sel1_s = t * 4 + 2; k2_s = k - b; } b = nb;
        nb = b + l3; if (b <= k && k < nb) { sel1_s = t * 4 + 3; k2_s = k - b; } b = nb;
    }
    __syncthreads();
    unsigned sel1 = sel1_s, k2 = k2_s;

    // pass 2: bits [9:0]
    for (int i = t; i < 1024; i += 256) h[i] = 0u;
    __syncthreads();
    for (unsigned i = t; i < count; i += 256) {
        unsigned c = cand[i];
        if (((c >> 10) & 1023u) == sel1) atomicAdd(&h[c & 1023u], 1u);
    }
    __syncthreads();
    {
        unsigned l0 = h[t * 4], l1 = h[t * 4 + 1], l2 = h[t * 4 + 2], l3 = h[t * 4 + 3];
        unsigned s = l0 + l1 + l2 + l3;
        unsigned b = block_excl_scan(s, tmp);
        unsigned nb;
        nb = b + l0; if (b <= k2 && k2 < nb) sel2_s = t * 4 + 0; b = nb;
        nb = b + l1; if (b <= k2 && k2 < nb) sel2_s = t * 4 + 1; b = nb;
        nb = b + l2; if (b <= k2 && k2 < nb) sel2_s = t * 4 + 2; b = nb;
        nb = b + l3; if (b <= k2 && k2 < nb) sel2_s = t * 4 + 3; b = nb;
    }
    __syncthreads();
    if (t == 0) {
        unsigned key = (ws[WS_BIN] << 20) | (sel1 << 10) | sel2_s;
        unsigned u = (key & 0x80000000u) ? (key & 0x7fffffffu) : ~key;
        ws[WS_MEDIAN] = u;
    }
}

// ---------------- fused threshold + 7x7 maxpool + mask ----------------
#define TX 128
#define TY 32
#define HXP 136         // TX + 6, padded stride
#define HY 38           // TY + 6
#define IMG_W 1024
#define IMG_H 1024

__global__ __launch_bounds__(256) void k_pool(const float* __restrict__ x,
                                              float* __restrict__ out,
                                              const unsigned* __restrict__ ws) {
    __shared__ float xt[HY][HXP];
    __shared__ float rm[HY][TX];
    float med = __uint_as_float(ws[WS_MEDIAN]);
    int c0 = blockIdx.x * TX;
    int r0 = blockIdx.y * TY;
    const float* img = x + (size_t)blockIdx.z * (IMG_W * IMG_H);
    float* outp = out + (size_t)blockIdx.z * (IMG_W * IMG_H);

    int rbase = threadIdx.x / 128;   // 0 or 1
    int c = threadIdx.x % 128;

    // load tile + halo, thresholded; out-of-image = -inf
    for (int rr = rbase; rr < HY; rr += 2) {
        int gr = r0 + rr - 3;
        {
            int gc = c0 + c - 3;
            float v = -INFINITY;
            if ((unsigned)gr < (unsigned)IMG_H && (unsigned)gc < (unsigned)IMG_W) {
                float f = img[gr * IMG_W + gc];
                v = (f > med) ? f : 0.0f;
            }
            xt[rr][c] = v;
        }
        if (c < 6) {
            int gc = c0 + c + 128 - 3;
            float v = -INFINITY;
            if ((unsigned)gr < (unsigned)IMG_H && (unsigned)gc < (unsigned)IMG_W) {
                float f = img[gr * IMG_W + gc];
                v = (f > med) ? f : 0.0f;
            }
            xt[rr][c + 128] = v;
        }
    }
    __syncthreads();

    // horizontal 7-max
    for (int rr = rbase; rr < HY; rr += 2) {
        float m = xt[rr][c];
        #pragma unroll
        for (int j = 1; j < 7; ++j) m = fmaxf(m, xt[rr][c + j]);
        rm[rr][c] = m;
    }
    __syncthreads();

    // vertical 7-max + mask + write
    for (int rr = rbase; rr < TY; rr += 2) {
        float y = rm[rr][c];
        #pragma unroll
        for (int j = 1; j < 7; ++j) y = fmaxf(y, rm[rr + j][c]);
        float v = xt[rr + 3][c + 3];
        outp[(r0 + rr) * IMG_W + (c0 + c)] = (v == y) ? v : 0.0f;
    }
}

extern "C" void kernel_launch(void* const* d_in, const int* in_sizes, int n_in,
                              void* d_out, int out_size, void* d_ws, size_t ws_size,
                              hipStream_t stream) {
    const float* x = (const float*)d_in[0];
    float* out = (float*)d_out;
    unsigned* ws = (unsigned*)d_ws;
    unsigned* cand = (unsigned*)d_out;   // scratch; fully overwritten by k_pool

    int n = in_sizes[0];                  // 16,777,216
    int n4 = n / 4;
    unsigned k = (unsigned)((n - 1) / 2); // lower median rank

    // zero hist + candidate counter
    hipMemsetAsync(d_ws, 0, (WS_CAND_CNT + 1) * sizeof(unsigned), stream);

    dim3 blk(256);
    k_hist<<<dim3(2048), blk, 0, stream>>>(x, ws, n4);
    k_scan<<<dim3(1), blk, 0, stream>>>(ws, k);
    k_collect<<<dim3(2048), blk, 0, stream>>>(x, ws, cand, n4);
    k_select<<<dim3(1), blk, 0, stream>>>(ws, cand);

    dim3 pgrid(IMG_W / TX, IMG_H / TY, 16);
    k_pool<<<pgrid, blk, 0, stream>>>(x, out, ws);
}

// Round 3
// 102.290 us; speedup vs baseline: 2.1926x; 1.3574x over previous
//
#include <hip/hip_runtime.h>
#include <stdint.h>

// ---------------- workspace layout (uint32 words) ----------------
#define HIST_SIZE   4096        // top-12-bit histogram
#define WS_HIST     0
#define WS_CAND_CNT 4096
#define WS_BIN      4097
#define WS_KINBIN   4098
#define WS_MEDIAN   4099

// monotonic key: orders float bit patterns ascending
__device__ __forceinline__ unsigned f2key(float f) {
    unsigned u = __float_as_uint(f);
    return (u & 0x80000000u) ? ~u : (u | 0x80000000u);
}

// 256-thread exclusive prefix sum (Hillis-Steele in LDS). tmp is 256 words.
__device__ __forceinline__ unsigned block_excl_scan(unsigned s, unsigned* tmp) {
    int t = threadIdx.x;
    tmp[t] = s;
    __syncthreads();
    unsigned acc = s;
    #pragma unroll
    for (int off = 1; off < 256; off <<= 1) {
        unsigned v = (t >= off) ? tmp[t - off] : 0u;
        __syncthreads();
        acc += v;
        tmp[t] = acc;
        __syncthreads();
    }
    return acc - s;   // exclusive prefix
}

// ---------------- pass 1: histogram of top 12 bits ----------------
__global__ __launch_bounds__(256) void k_hist(const float* __restrict__ x,
                                              unsigned* __restrict__ ws, int n4) {
    __shared__ unsigned lh[HIST_SIZE];
    for (int i = threadIdx.x; i < HIST_SIZE; i += 256) lh[i] = 0u;
    __syncthreads();
    const float4* x4 = (const float4*)x;
    int stride = gridDim.x * blockDim.x;
    for (int i = blockIdx.x * blockDim.x + threadIdx.x; i < n4; i += stride) {
        float4 v = x4[i];
        atomicAdd(&lh[f2key(v.x) >> 20], 1u);
        atomicAdd(&lh[f2key(v.y) >> 20], 1u);
        atomicAdd(&lh[f2key(v.z) >> 20], 1u);
        atomicAdd(&lh[f2key(v.w) >> 20], 1u);
    }
    __syncthreads();
    for (int i = threadIdx.x; i < HIST_SIZE; i += 256) {
        unsigned c = lh[i];
        if (c) atomicAdd(&ws[WS_HIST + i], c);
    }
}

// ---------------- find bin containing rank k (parallel scan) ----------------
__global__ __launch_bounds__(256) void k_scan(unsigned* __restrict__ ws, unsigned k) {
    __shared__ unsigned tmp[256];
    int t = threadIdx.x;
    unsigned local[16];
    unsigned s = 0;
    #pragma unroll
    for (int j = 0; j < 16; ++j) { local[j] = ws[WS_HIST + t * 16 + j]; s += local[j]; }
    unsigned b = block_excl_scan(s, tmp);
    #pragma unroll
    for (int j = 0; j < 16; ++j) {
        unsigned nb = b + local[j];
        if (b <= k && k < nb) {
            ws[WS_BIN] = (unsigned)(t * 16 + j);
            ws[WS_KINBIN] = k - b;
        }
        b = nb;
    }
}

// ---------------- pass 2: collect candidates in selected bin ----------------
__global__ __launch_bounds__(256) void k_collect(const float* __restrict__ x,
                                                 unsigned* __restrict__ ws,
                                                 unsigned* __restrict__ cand, int n4) {
    unsigned B = ws[WS_BIN];
    const float4* x4 = (const float4*)x;
    int stride = gridDim.x * blockDim.x;
    for (int i = blockIdx.x * blockDim.x + threadIdx.x; i < n4; i += stride) {
        float4 v = x4[i];
        unsigned k0 = f2key(v.x), k1 = f2key(v.y), k2 = f2key(v.z), k3 = f2key(v.w);
        if ((k0 >> 20) == B) cand[atomicAdd(&ws[WS_CAND_CNT], 1u)] = k0;
        if ((k1 >> 20) == B) cand[atomicAdd(&ws[WS_CAND_CNT], 1u)] = k1;
        if ((k2 >> 20) == B) cand[atomicAdd(&ws[WS_CAND_CNT], 1u)] = k2;
        if ((k3 >> 20) == B) cand[atomicAdd(&ws[WS_CAND_CNT], 1u)] = k3;
    }
}

// ---------------- select low 20 bits (single block, parallel scans) ----------------
__global__ __launch_bounds__(256) void k_select(unsigned* __restrict__ ws,
                                                const unsigned* __restrict__ cand) {
    __shared__ unsigned h[1024];
    __shared__ unsigned tmp[256];
    __shared__ unsigned sel1_s, k2_s, sel2_s;
    unsigned count = ws[WS_CAND_CNT];
    unsigned k = ws[WS_KINBIN];
    int t = threadIdx.x;

    // pass 1: bits [19:10]
    for (int i = t; i < 1024; i += 256) h[i] = 0u;
    __syncthreads();
    for (unsigned i = t; i < count; i += 256) atomicAdd(&h[(cand[i] >> 10) & 1023u], 1u);
    __syncthreads();
    {
        unsigned l0 = h[t * 4], l1 = h[t * 4 + 1], l2 = h[t * 4 + 2], l3 = h[t * 4 + 3];
        unsigned s = l0 + l1 + l2 + l3;
        unsigned b = block_excl_scan(s, tmp);
        unsigned nb;
        nb = b + l0; if (b <= k && k < nb) { sel1_s = t * 4 + 0; k2_s = k - b; } b = nb;
        nb = b + l1; if (b <= k && k < nb) { sel1_s = t * 4 + 1; k2_s = k - b; } b = nb;
        nb = b + l2; if (b <= k && k < nb) { sel1_s = t * 4 + 2; k2_s = k - b; } b = nb;
        nb = b + l3; if (b <= k && k < nb) { sel1_s = t * 4 + 3; k2_s = k - b; } b = nb;
    }
    __syncthreads();
    unsigned sel1 = sel1_s, k2 = k2_s;

    // pass 2: bits [9:0]
    for (int i = t; i < 1024; i += 256) h[i] = 0u;
    __syncthreads();
    for (unsigned i = t; i < count; i += 256) {
        unsigned c = cand[i];
        if (((c >> 10) & 1023u) == sel1) atomicAdd(&h[c & 1023u], 1u);
    }
    __syncthreads();
    {
        unsigned l0 = h[t * 4], l1 = h[t * 4 + 1], l2 = h[t * 4 + 2], l3 = h[t * 4 + 3];
        unsigned s = l0 + l1 + l2 + l3;
        unsigned b = block_excl_scan(s, tmp);
        unsigned nb;
        nb = b + l0; if (b <= k2 && k2 < nb) sel2_s = t * 4 + 0; b = nb;
        nb = b + l1; if (b <= k2 && k2 < nb) sel2_s = t * 4 + 1; b = nb;
        nb = b + l2; if (b <= k2 && k2 < nb) sel2_s = t * 4 + 2; b = nb;
        nb = b + l3; if (b <= k2 && k2 < nb) sel2_s = t * 4 + 3; b = nb;
    }
    __syncthreads();
    if (t == 0) {
        unsigned key = (ws[WS_BIN] << 20) | (sel1 << 10) | sel2_s;
        unsigned u = (key & 0x80000000u) ? (key & 0x7fffffffu) : ~key;
        ws[WS_MEDIAN] = u;
    }
}

// ---- fused threshold + 7x7 maxpool + mask: register-ring, no LDS, no barriers ----
#define IMG_W 1024
#define IMG_H 1024
#define PTY 16          // output rows per wave strip

__device__ __forceinline__ float4 ldthr(const float* p, bool ok, float med) {
    if (!ok) return make_float4(-INFINITY, -INFINITY, -INFINITY, -INFINITY);
    float4 f = *(const float4*)p;
    f.x = (f.x > med) ? f.x : 0.0f;
    f.y = (f.y > med) ? f.y : 0.0f;
    f.z = (f.z > med) ? f.z : 0.0f;
    f.w = (f.w > med) ? f.w : 0.0f;
    return f;
}

__global__ __launch_bounds__(256) void k_pool(const float* __restrict__ x,
                                              float* __restrict__ out,
                                              const unsigned* __restrict__ ws) {
    float med = __uint_as_float(ws[WS_MEDIAN]);
    int gwave = blockIdx.x * 4 + (threadIdx.x >> 6);
    int lane = threadIdx.x & 63;
    // 16 images x 64 row-strips x 4 col-tiles = 4096 waves
    int ct  = gwave & 3;
    int rs  = (gwave >> 2) & 63;
    int img = gwave >> 8;
    const float* imgp = x + (size_t)img * (IMG_W * IMG_H);
    float* outp = out + (size_t)img * (IMG_W * IMG_H);
    int r0 = rs * PTY;
    int cbase = ct * 256 + lane * 4;           // this lane's 4 output cols
    bool aok = (cbase >= 4);                   // left chunk in-image
    bool cok = (cbase <= IMG_W - 8);           // right chunk in-image

    float4 hm[7];   // horizontal-max ring (static indexing via full unroll)
    float4 xc[4];   // thresholded center ring (delay 3)

    #pragma unroll
    for (int i = 0; i < PTY + 6; ++i) {
        int gr = r0 + i - 3;
        bool rok = ((unsigned)gr < (unsigned)IMG_H);
        const float* rp = imgp + (size_t)gr * IMG_W + cbase;
        float4 a = ldthr(rp - 4, rok && aok, med);
        float4 b = ldthr(rp,     rok,        med);
        float4 c = ldthr(rp + 4, rok && cok, med);
        // all 4 windows fully contain chunk b
        float mb = fmaxf(fmaxf(b.x, b.y), fmaxf(b.z, b.w));
        float4 h;
        h.x = fmaxf(fmaxf(a.y, a.z), fmaxf(a.w, mb));
        h.y = fmaxf(fmaxf(a.z, a.w), fmaxf(mb, c.x));
        h.z = fmaxf(fmaxf(a.w, mb),  fmaxf(c.x, c.y));
        h.w = fmaxf(fmaxf(mb, c.x),  fmaxf(c.y, c.z));
        hm[i % 7] = h;
        xc[i % 4] = b;
        if (i >= 6) {
            float4 y = hm[0];
            #pragma unroll
            for (int j = 1; j < 7; ++j) {
                y.x = fmaxf(y.x, hm[j].x);
                y.y = fmaxf(y.y, hm[j].y);
                y.z = fmaxf(y.z, hm[j].z);
                y.w = fmaxf(y.w, hm[j].w);
            }
            float4 v = xc[(i - 3) % 4];
            float4 o;
            o.x = (v.x == y.x) ? v.x : 0.0f;
            o.y = (v.y == y.y) ? v.y : 0.0f;
            o.z = (v.z == y.z) ? v.z : 0.0f;
            o.w = (v.w == y.w) ? v.w : 0.0f;
            int orow = gr - 3;
            *(float4*)(outp + (size_t)orow * IMG_W + cbase) = o;
        }
    }
}

extern "C" void kernel_launch(void* const* d_in, const int* in_sizes, int n_in,
                              void* d_out, int out_size, void* d_ws, size_t ws_size,
                              hipStream_t stream) {
    const float* x = (const float*)d_in[0];
    float* out = (float*)d_out;
    unsigned* ws = (unsigned*)d_ws;
    unsigned* cand = (unsigned*)d_out;   // scratch; fully overwritten by k_pool

    int n = in_sizes[0];                  // 16,777,216
    int n4 = n / 4;
    unsigned k = (unsigned)((n - 1) / 2); // lower median rank

    // zero hist + candidate counter
    hipMemsetAsync(d_ws, 0, (WS_CAND_CNT + 1) * sizeof(unsigned), stream);

    dim3 blk(256);
    k_hist<<<dim3(2048), blk, 0, stream>>>(x, ws, n4);
    k_scan<<<dim3(1), blk, 0, stream>>>(ws, k);
    k_collect<<<dim3(2048), blk, 0, stream>>>(x, ws, cand, n4);
    k_select<<<dim3(1), blk, 0, stream>>>(ws, cand);

    // 16 images x 64 strips x 4 col-tiles = 4096 waves = 1024 blocks
    k_pool<<<dim3(1024), blk, 0, stream>>>(x, out, ws);
}